// Round 7
// baseline (351.844 us; speedup 1.0000x reference)
//
#include <hip/hip_runtime.h>

#define NUSERS 100000
#define NITEMS 50000
#define DIM 64
#define NNZ 1600000
#define ALPHA 0.1f
#define TROWS (NUSERS + NITEMS)   // 150000 combined rows
#define LSTRIDE (TROWS * DIM)
#define NEDGES (2 * NNZ)          // 3.2M combined edges

#define BROWS 128                           // rows per bucket
#define NBUCK ((TROWS + BROWS - 1) / BROWS) // 1172

#define CH_H 4096                               // edges per hist block
#define NCHUNK_H ((NEDGES + CH_H - 1) / CH_H)   // 782
#define CH_S 4096                               // edges per scatter block
#define NCHUNK_S ((NEDGES + CH_S - 1) / CH_S)   // 782

typedef float vfloat4 __attribute__((ext_vector_type(4)));

__device__ __forceinline__ unsigned short f2bf(float f) {
    unsigned u = __float_as_uint(f);
    unsigned r = (u + 0x7FFFu + ((u >> 16) & 1u)) >> 16;   // RNE
    return (unsigned short)r;
}

__device__ __forceinline__ int2 nt_load_int2(const int2* p) {
    unsigned long long u = __builtin_nontemporal_load((const unsigned long long*)p);
    int2 r;
    r.x = (int)(unsigned)(u & 0xFFFFFFFFull);
    r.y = (int)(unsigned)(u >> 32);
    return r;
}

// ---------------- layer-0 copy (+ optional bf16 table) ----------------
template <int MAKE_BF16>
__global__ __launch_bounds__(256) void init_copy_kernel(const float4* __restrict__ ue,
                                                        const float4* __restrict__ ie,
                                                        float4* __restrict__ out,
                                                        ushort4* __restrict__ xb0) {
    const int nU4 = NUSERS * DIM / 4;
    const int nT4 = TROWS * DIM / 4;
    int i = blockIdx.x * 256 + threadIdx.x;
    if (i >= nT4) return;
    float4 v = (i < nU4) ? ue[i] : ie[i - nU4];
    out[i] = v;
    if (MAKE_BF16) {
        ushort4 b;
        b.x = f2bf(v.x); b.y = f2bf(v.y); b.z = f2bf(v.z); b.w = f2bf(v.w);
        xb0[i] = b;
    }
}

// ---------------- bucket histogram (block-privatized, int LDS atomics) ----------------
__global__ __launch_bounds__(256) void bucket_hist_kernel(const int* __restrict__ ui_rows,
                                                          const int* __restrict__ iu_rows,
                                                          int* __restrict__ gcounts) {
    __shared__ int h[NBUCK];
    for (int t = threadIdx.x; t < NBUCK; t += 256) h[t] = 0;
    __syncthreads();
    int base = blockIdx.x * CH_H;
    for (int j = threadIdx.x; j < CH_H; j += 256) {
        int i = base + j;
        if (i >= NEDGES) break;
        int crow = (i < NNZ) ? ui_rows[i] : (NUSERS + iu_rows[i - NNZ]);
        atomicAdd(&h[crow >> 7], 1);
    }
    __syncthreads();
    for (int t = threadIdx.x; t < NBUCK; t += 256) {
        int c = h[t];
        if (c) atomicAdd(&gcounts[t], c);
    }
}

// ---------------- exclusive scan of bucket counts (one wave) ----------------
__global__ void scan_buckets_kernel(const int* __restrict__ gcounts,
                                    int* __restrict__ gbase,
                                    int* __restrict__ gcursor,
                                    int* __restrict__ rowptr) {
    int lane = threadIdx.x;   // blockDim = 64, single wave
    int carry = 0;
    for (int b0 = 0; b0 < NBUCK; b0 += 64) {
        int idx = b0 + lane;
        int c = (idx < NBUCK) ? gcounts[idx] : 0;
        int x = c;
        for (int off = 1; off < 64; off <<= 1) {
            int u = __shfl_up(x, off, 64);
            if (lane >= off) x += u;
        }
        int excl = carry + x - c;
        if (idx < NBUCK) { gbase[idx] = excl; gcursor[idx] = excl; }
        carry += __shfl(x, 63, 64);
    }
    if (lane == 0) rowptr[TROWS] = NEDGES;   // sentinel
}

// ---------------- binned scatter: contiguous per-(block,bucket) runs ----------------
// payload word0 = src | (row_local << 18)   (src < 2^18, row_local < 128)
__global__ __launch_bounds__(256) void bin_scatter_kernel(
    const int* __restrict__ ui_rows, const int* __restrict__ ui_cols,
    const float* __restrict__ ui_vals,
    const int* __restrict__ iu_rows, const int* __restrict__ iu_cols,
    const float* __restrict__ iu_vals,
    int* __restrict__ gcursor, int2* __restrict__ binned)
{
    __shared__ int h[NBUCK];
    __shared__ int bbase[NBUCK];
    for (int t = threadIdx.x; t < NBUCK; t += 256) h[t] = 0;
    __syncthreads();
    int base = blockIdx.x * CH_S;
    for (int j = threadIdx.x; j < CH_S; j += 256) {
        int i = base + j;
        if (i >= NEDGES) break;
        int crow = (i < NNZ) ? ui_rows[i] : (NUSERS + iu_rows[i - NNZ]);
        atomicAdd(&h[crow >> 7], 1);
    }
    __syncthreads();
    for (int t = threadIdx.x; t < NBUCK; t += 256) {
        int c = h[t];
        bbase[t] = c ? atomicAdd(&gcursor[t], c) : 0;
        h[t] = 0;
    }
    __syncthreads();
    for (int j = threadIdx.x; j < CH_S; j += 256) {
        int i = base + j;
        if (i >= NEDGES) break;
        int crow, src; float val;
        if (i < NNZ) {
            crow = ui_rows[i]; src = NUSERS + ui_cols[i]; val = ui_vals[i];
        } else {
            int k = i - NNZ;
            crow = NUSERS + iu_rows[k]; src = iu_cols[k]; val = iu_vals[k];
        }
        int b = crow >> 7;
        int off = atomicAdd(&h[b], 1);
        binned[bbase[b] + off] = make_int2(src | ((crow & 127) << 18), __float_as_int(val));
    }
}

// ---------------- bucket-local CSR sort: binned -> binned2 (row-sorted) ----------------
__global__ __launch_bounds__(512) void csr_sort_kernel(
    const int* __restrict__ gbase, const int* __restrict__ gcounts,
    const int2* __restrict__ binned, int2* __restrict__ binned2,
    int* __restrict__ rowptr)
{
    __shared__ int h[BROWS];
    __shared__ int off[BROWS];
    __shared__ int cur[BROWS];
    int b = blockIdx.x;
    int s = gbase[b];
    int n = gcounts[b];
    int t = threadIdx.x;
    if (t < BROWS) h[t] = 0;
    __syncthreads();
    for (int j = t; j < n; j += 512)
        atomicAdd(&h[((unsigned)binned[s + j].x) >> 18], 1);
    __syncthreads();
    if (t < BROWS) off[t] = h[t];
    __syncthreads();
    for (int d = 1; d < BROWS; d <<= 1) {
        int v = 0;
        if (t < BROWS && t >= d) v = off[t - d];
        __syncthreads();
        if (t < BROWS) off[t] += v;
        __syncthreads();
    }
    if (t < BROWS) {
        int excl = off[t] - h[t];     // exclusive scan
        cur[t] = excl;
        int row = b * BROWS + t;
        if (row < TROWS) rowptr[row] = s + excl;
    }
    __syncthreads();
    for (int j = t; j < n; j += 512) {
        int2 m = binned[s + j];
        unsigned w = (unsigned)m.x;
        int pos = atomicAdd(&cur[w >> 18], 1);
        binned2[s + pos] = make_int2((int)(w & 0x3FFFFu), m.y);
    }
}

// ---------------- CSR pull: one wave per output row, register accumulate ----------------
// Wave = 4 edge-groups x 16 lanes; group covers the full feature row of its
// edge (bf16: uint2/lane = 128B; f32: float4/lane = 256B). 4-deep unroll:
// 16 independent gathers in flight per wave. Edge stream and f32 output use
// nontemporal access so L2 stays reserved for the gather table.
template <int USE_BF16>
__device__ __forceinline__ void edge_fma(int src, float v,
                                         const unsigned short* __restrict__ xb,
                                         const float* __restrict__ xf,
                                         int sub, float4& acc) {
    if (USE_BF16) {
        uint2 x = *(const uint2*)(xb + (size_t)src * DIM + sub * 4);
        acc.x = fmaf(v, __uint_as_float(x.x << 16), acc.x);
        acc.y = fmaf(v, __uint_as_float(x.x & 0xFFFF0000u), acc.y);
        acc.z = fmaf(v, __uint_as_float(x.y << 16), acc.z);
        acc.w = fmaf(v, __uint_as_float(x.y & 0xFFFF0000u), acc.w);
    } else {
        float4 x = *(const float4*)(xf + (size_t)src * DIM + sub * 4);
        acc.x = fmaf(v, x.x, acc.x);
        acc.y = fmaf(v, x.y, acc.y);
        acc.z = fmaf(v, x.z, acc.z);
        acc.w = fmaf(v, x.w, acc.w);
    }
}

template <int USE_BF16, int WRITE_BF16>
__global__ __launch_bounds__(256) void pull_csr_kernel(
    const int* __restrict__ rowptr, const int2* __restrict__ cc,
    const unsigned short* __restrict__ xb_prev,  // bf16 combined prev layer
    const float* __restrict__ xf_prev,           // f32 combined prev layer
    const float4* __restrict__ ue4, const float4* __restrict__ ie4,
    float4* __restrict__ outL4,                  // combined f32 output layer
    ushort4* __restrict__ xb_next)               // bf16 table for next layer
{
    int gid = blockIdx.x * 256 + threadIdx.x;
    int r = gid >> 6;
    if (r >= TROWS) return;
    int lane = threadIdx.x & 63;
    int g = lane >> 4;        // edge slot within wave: 0..3
    int sub = lane & 15;      // 4-float slot within feature row

    float4 acc = make_float4(0.f, 0.f, 0.f, 0.f);
    int end = rowptr[r + 1];
    int e = rowptr[r] + g;

    // 4-deep: 4 independent gathers in flight per group (16 per wave)
    for (; e + 12 < end; e += 16) {
        int2 m0 = nt_load_int2(&cc[e]);
        int2 m1 = nt_load_int2(&cc[e + 4]);
        int2 m2 = nt_load_int2(&cc[e + 8]);
        int2 m3 = nt_load_int2(&cc[e + 12]);
        edge_fma<USE_BF16>(m0.x, __int_as_float(m0.y), xb_prev, xf_prev, sub, acc);
        edge_fma<USE_BF16>(m1.x, __int_as_float(m1.y), xb_prev, xf_prev, sub, acc);
        edge_fma<USE_BF16>(m2.x, __int_as_float(m2.y), xb_prev, xf_prev, sub, acc);
        edge_fma<USE_BF16>(m3.x, __int_as_float(m3.y), xb_prev, xf_prev, sub, acc);
    }
    for (; e < end; e += 4) {
        int2 m0 = nt_load_int2(&cc[e]);
        edge_fma<USE_BF16>(m0.x, __int_as_float(m0.y), xb_prev, xf_prev, sub, acc);
    }

    // reduce the 4 edge-groups: lanes {sub, sub+16, sub+32, sub+48}
    acc.x += __shfl_xor(acc.x, 16, 64);
    acc.y += __shfl_xor(acc.y, 16, 64);
    acc.z += __shfl_xor(acc.z, 16, 64);
    acc.w += __shfl_xor(acc.w, 16, 64);
    acc.x += __shfl_xor(acc.x, 32, 64);
    acc.y += __shfl_xor(acc.y, 32, 64);
    acc.z += __shfl_xor(acc.z, 32, 64);
    acc.w += __shfl_xor(acc.w, 32, 64);

    if (g == 0) {
        float4 e0 = (r < NUSERS) ? ue4[(size_t)r * 16 + sub]
                                 : ie4[(size_t)(r - NUSERS) * 16 + sub];
        acc.x = fmaf(ALPHA, e0.x, acc.x);
        acc.y = fmaf(ALPHA, e0.y, acc.y);
        acc.z = fmaf(ALPHA, e0.z, acc.z);
        acc.w = fmaf(ALPHA, e0.w, acc.w);
        vfloat4 av; av.x = acc.x; av.y = acc.y; av.z = acc.z; av.w = acc.w;
        __builtin_nontemporal_store(av, (vfloat4*)(outL4 + (size_t)r * 16 + sub));
        if (WRITE_BF16) {
            ushort4 bb;
            bb.x = f2bf(acc.x); bb.y = f2bf(acc.y);
            bb.z = f2bf(acc.z); bb.w = f2bf(acc.w);
            xb_next[(size_t)r * 16 + sub] = bb;
        }
    }
}

// ---------------- fallback (round-1 atomic path) ----------------
__global__ __launch_bounds__(256) void init_out_kernel(const float4* __restrict__ ue,
                                                       const float4* __restrict__ ie,
                                                       float4* __restrict__ out) {
    const int nU4 = NUSERS * DIM / 4;
    const int nT4 = TROWS * DIM / 4;
    int i = blockIdx.x * 256 + threadIdx.x;
    if (i >= nT4) return;
    float4 v = (i < nU4) ? ue[i] : ie[i - nU4];
    out[i] = v;
    float4 a = make_float4(ALPHA * v.x, ALPHA * v.y, ALPHA * v.z, ALPHA * v.w);
    out[nT4 + i] = a;
    out[2 * nT4 + i] = a;
}

__global__ __launch_bounds__(256) void spmm_layer_kernel(
    const int* __restrict__ ui_rows, const int* __restrict__ ui_cols,
    const float* __restrict__ ui_vals,
    const int* __restrict__ iu_rows, const int* __restrict__ iu_cols,
    const float* __restrict__ iu_vals,
    const float* __restrict__ x_items, const float* __restrict__ x_users,
    float* __restrict__ y_users, float* __restrict__ y_items)
{
    unsigned tid = blockIdx.x * 256u + threadIdx.x;
    unsigned d = tid & 63u;
    unsigned e = tid >> 6;
    if (e < NNZ) {
        int r = ui_rows[e];
        int c = ui_cols[e];
        float v = ui_vals[e];
        atomicAdd(&y_users[r * DIM + d], v * x_items[c * DIM + d]);
    } else {
        e -= NNZ;
        if (e < NNZ) {
            int r = iu_rows[e];
            int c = iu_cols[e];
            float v = iu_vals[e];
            atomicAdd(&y_items[r * DIM + d], v * x_users[c * DIM + d]);
        }
    }
}

extern "C" void kernel_launch(void* const* d_in, const int* in_sizes, int n_in,
                              void* d_out, int out_size, void* d_ws, size_t ws_size,
                              hipStream_t stream) {
    const float* ue      = (const float*)d_in[0];
    const float* ie      = (const float*)d_in[1];
    const float* ui_vals = (const float*)d_in[2];
    const float* iu_vals = (const float*)d_in[3];
    const int*   ui_rows = (const int*)d_in[4];
    const int*   ui_cols = (const int*)d_in[5];
    const int*   iu_rows = (const int*)d_in[6];
    const int*   iu_cols = (const int*)d_in[7];
    float* out = (float*)d_out;

    float* L1 = out + (size_t)LSTRIDE;
    float* L2 = out + (size_t)2 * LSTRIDE;

    // ws layout: gcounts[1280] gbase[1280] gcursor[1280] rowptr[150032]
    //            | binned int2[NEDGES] | binned2 int2[NEDGES]
    //            | xb0 ushort[TROWS*64] | xb1 ushort[TROWS*64]
    const size_t NB_PAD = 1280;
    const size_t RP_PAD = 150032;
    const size_t hdr_bytes    = (NB_PAD * 3 + RP_PAD) * 4;   // 615488, 16B-aligned
    const size_t binned_bytes = (size_t)NEDGES * 8;          // 25.6 MB
    const size_t xb_bytes     = (size_t)TROWS * DIM * 2;     // 19.2 MB
    const size_t need_f32  = hdr_bytes + 2 * binned_bytes;             // ~51.8 MB
    const size_t need_bf16 = need_f32 + 2 * xb_bytes;                  // ~90.2 MB

    if (ws_size < need_f32) {
        // last-resort fallback: atomic scatter path (round-1, known-good)
        const int nT4 = TROWS * DIM / 4;
        init_out_kernel<<<(nT4 + 255) / 256, 256, 0, stream>>>(
            (const float4*)ue, (const float4*)ie, (float4*)out);
        float* u1 = L1; float* i1 = L1 + (size_t)NUSERS * DIM;
        float* u2 = L2; float* i2 = L2 + (size_t)NUSERS * DIM;
        const unsigned nblocks = (2u * NNZ * 64u) / 256u;
        spmm_layer_kernel<<<nblocks, 256, 0, stream>>>(
            ui_rows, ui_cols, ui_vals, iu_rows, iu_cols, iu_vals, ie, ue, u1, i1);
        spmm_layer_kernel<<<nblocks, 256, 0, stream>>>(
            ui_rows, ui_cols, ui_vals, iu_rows, iu_cols, iu_vals, i1, u1, u2, i2);
        return;
    }

    int* gcounts = (int*)d_ws;
    int* gbase   = gcounts + NB_PAD;
    int* gcursor = gbase + NB_PAD;
    int* rowptr  = gcursor + NB_PAD;
    int2* binned  = (int2*)((char*)d_ws + hdr_bytes);
    int2* binned2 = (int2*)((char*)binned + binned_bytes);
    unsigned short* xb0 = (unsigned short*)((char*)binned2 + binned_bytes);
    unsigned short* xb1 = xb0 + (size_t)TROWS * DIM;

    const bool use_bf16 = (ws_size >= need_bf16);

    hipMemsetAsync(gcounts, 0, NB_PAD * sizeof(int), stream);

    const int nT4 = TROWS * DIM / 4;
    if (use_bf16)
        init_copy_kernel<1><<<(nT4 + 255) / 256, 256, 0, stream>>>(
            (const float4*)ue, (const float4*)ie, (float4*)out, (ushort4*)xb0);
    else
        init_copy_kernel<0><<<(nT4 + 255) / 256, 256, 0, stream>>>(
            (const float4*)ue, (const float4*)ie, (float4*)out, nullptr);

    bucket_hist_kernel<<<NCHUNK_H, 256, 0, stream>>>(ui_rows, iu_rows, gcounts);
    scan_buckets_kernel<<<1, 64, 0, stream>>>(gcounts, gbase, gcursor, rowptr);
    bin_scatter_kernel<<<NCHUNK_S, 256, 0, stream>>>(
        ui_rows, ui_cols, ui_vals, iu_rows, iu_cols, iu_vals, gcursor, binned);
    csr_sort_kernel<<<NBUCK, 512, 0, stream>>>(gbase, gcounts, binned, binned2, rowptr);

    const float4* ue4 = (const float4*)ue;
    const float4* ie4 = (const float4*)ie;
    const int pgrid = (TROWS * DIM) / 256;   // 37500 blocks
    if (use_bf16) {
        pull_csr_kernel<1, 1><<<pgrid, 256, 0, stream>>>(
            rowptr, binned2, xb0, nullptr, ue4, ie4, (float4*)L1, (ushort4*)xb1);
        pull_csr_kernel<1, 0><<<pgrid, 256, 0, stream>>>(
            rowptr, binned2, xb1, nullptr, ue4, ie4, (float4*)L2, nullptr);
    } else {
        pull_csr_kernel<0, 0><<<pgrid, 256, 0, stream>>>(
            rowptr, binned2, nullptr, out, ue4, ie4, (float4*)L1, nullptr);
        pull_csr_kernel<0, 0><<<pgrid, 256, 0, stream>>>(
            rowptr, binned2, nullptr, L1, ue4, ie4, (float4*)L2, nullptr);
    }
}

// Round 8
// 324.195 us; speedup vs baseline: 1.0853x; 1.0853x over previous
//
#include <hip/hip_runtime.h>

#define NUSERS 100000
#define NITEMS 50000
#define DIM 64
#define NNZ 1600000
#define ALPHA 0.1f
#define TROWS (NUSERS + NITEMS)   // 150000 combined rows
#define LSTRIDE (TROWS * DIM)
#define NEDGES (2 * NNZ)          // 3.2M combined edges

#define BROWS 128                           // rows per bucket
#define NBUCK ((TROWS + BROWS - 1) / BROWS) // 1172

#define CH_H 4096                               // edges per hist block
#define NCHUNK_H ((NEDGES + CH_H - 1) / CH_H)   // 782
#define CH_S 8192                               // edges per scatter block
#define NCHUNK_S ((NEDGES + CH_S - 1) / CH_S)   // 391

__device__ __forceinline__ unsigned short f2bf(float f) {
    unsigned u = __float_as_uint(f);
    unsigned r = (u + 0x7FFFu + ((u >> 16) & 1u)) >> 16;   // RNE
    return (unsigned short)r;
}

// ---------------- layer-0 copy (+ optional bf16 table) ----------------
template <int MAKE_BF16>
__global__ __launch_bounds__(256) void init_copy_kernel(const float4* __restrict__ ue,
                                                        const float4* __restrict__ ie,
                                                        float4* __restrict__ out,
                                                        ushort4* __restrict__ xb0) {
    const int nU4 = NUSERS * DIM / 4;
    const int nT4 = TROWS * DIM / 4;
    int i = blockIdx.x * 256 + threadIdx.x;
    if (i >= nT4) return;
    float4 v = (i < nU4) ? ue[i] : ie[i - nU4];
    out[i] = v;
    if (MAKE_BF16) {
        ushort4 b;
        b.x = f2bf(v.x); b.y = f2bf(v.y); b.z = f2bf(v.z); b.w = f2bf(v.w);
        xb0[i] = b;
    }
}

// ---------------- bucket histogram (block-privatized, int LDS atomics) ----------------
__global__ __launch_bounds__(256) void bucket_hist_kernel(const int* __restrict__ ui_rows,
                                                          const int* __restrict__ iu_rows,
                                                          int* __restrict__ gcounts) {
    __shared__ int h[NBUCK];
    for (int t = threadIdx.x; t < NBUCK; t += 256) h[t] = 0;
    __syncthreads();
    int base = blockIdx.x * CH_H;
    for (int j = threadIdx.x; j < CH_H; j += 256) {
        int i = base + j;
        if (i >= NEDGES) break;
        int crow = (i < NNZ) ? ui_rows[i] : (NUSERS + iu_rows[i - NNZ]);
        atomicAdd(&h[crow >> 7], 1);
    }
    __syncthreads();
    for (int t = threadIdx.x; t < NBUCK; t += 256) {
        int c = h[t];
        if (c) atomicAdd(&gcounts[t], c);
    }
}

// ---------------- exclusive scan of bucket counts (one wave) ----------------
__global__ void scan_buckets_kernel(const int* __restrict__ gcounts,
                                    int* __restrict__ gbase,
                                    int* __restrict__ gcursor,
                                    int* __restrict__ rowptr) {
    int lane = threadIdx.x;   // blockDim = 64, single wave
    int carry = 0;
    for (int b0 = 0; b0 < NBUCK; b0 += 64) {
        int idx = b0 + lane;
        int c = (idx < NBUCK) ? gcounts[idx] : 0;
        int x = c;
        for (int off = 1; off < 64; off <<= 1) {
            int u = __shfl_up(x, off, 64);
            if (lane >= off) x += u;
        }
        int excl = carry + x - c;
        if (idx < NBUCK) { gbase[idx] = excl; gcursor[idx] = excl; }
        carry += __shfl(x, 63, 64);
    }
    if (lane == 0) rowptr[TROWS] = NEDGES;   // sentinel
}

// ---------------- binned scatter: contiguous per-(block,bucket) runs ----------------
// payload word0 = src | (row_local << 18)   (src < 2^18, row_local < 128)
__global__ __launch_bounds__(512) void bin_scatter_kernel(
    const int* __restrict__ ui_rows, const int* __restrict__ ui_cols,
    const float* __restrict__ ui_vals,
    const int* __restrict__ iu_rows, const int* __restrict__ iu_cols,
    const float* __restrict__ iu_vals,
    int* __restrict__ gcursor, int2* __restrict__ binned)
{
    __shared__ int h[NBUCK];
    __shared__ int bbase[NBUCK];
    for (int t = threadIdx.x; t < NBUCK; t += 512) h[t] = 0;
    __syncthreads();
    int base = blockIdx.x * CH_S;
    for (int j = threadIdx.x; j < CH_S; j += 512) {
        int i = base + j;
        if (i >= NEDGES) break;
        int crow = (i < NNZ) ? ui_rows[i] : (NUSERS + iu_rows[i - NNZ]);
        atomicAdd(&h[crow >> 7], 1);
    }
    __syncthreads();
    for (int t = threadIdx.x; t < NBUCK; t += 512) {
        int c = h[t];
        bbase[t] = c ? atomicAdd(&gcursor[t], c) : 0;
        h[t] = 0;
    }
    __syncthreads();
    for (int j = threadIdx.x; j < CH_S; j += 512) {
        int i = base + j;
        if (i >= NEDGES) break;
        int crow, src; float val;
        if (i < NNZ) {
            crow = ui_rows[i]; src = NUSERS + ui_cols[i]; val = ui_vals[i];
        } else {
            int k = i - NNZ;
            crow = NUSERS + iu_rows[k]; src = iu_cols[k]; val = iu_vals[k];
        }
        int b = crow >> 7;
        int off = atomicAdd(&h[b], 1);
        binned[bbase[b] + off] = make_int2(src | ((crow & 127) << 18), __float_as_int(val));
    }
}

// ---------------- bucket-local CSR sort: binned -> binned2 (row-sorted) ----------------
__global__ __launch_bounds__(512) void csr_sort_kernel(
    const int* __restrict__ gbase, const int* __restrict__ gcounts,
    const int2* __restrict__ binned, int2* __restrict__ binned2,
    int* __restrict__ rowptr)
{
    __shared__ int h[BROWS];
    __shared__ int off[BROWS];
    __shared__ int cur[BROWS];
    int b = blockIdx.x;
    int s = gbase[b];
    int n = gcounts[b];
    int t = threadIdx.x;
    if (t < BROWS) h[t] = 0;
    __syncthreads();
    for (int j = t; j < n; j += 512)
        atomicAdd(&h[((unsigned)binned[s + j].x) >> 18], 1);
    __syncthreads();
    if (t < BROWS) off[t] = h[t];
    __syncthreads();
    for (int d = 1; d < BROWS; d <<= 1) {
        int v = 0;
        if (t < BROWS && t >= d) v = off[t - d];
        __syncthreads();
        if (t < BROWS) off[t] += v;
        __syncthreads();
    }
    if (t < BROWS) {
        int excl = off[t] - h[t];     // exclusive scan
        cur[t] = excl;
        int row = b * BROWS + t;
        if (row < TROWS) rowptr[row] = s + excl;
    }
    __syncthreads();
    for (int j = t; j < n; j += 512) {
        int2 m = binned[s + j];
        unsigned w = (unsigned)m.x;
        int pos = atomicAdd(&cur[w >> 18], 1);
        binned2[s + pos] = make_int2((int)(w & 0x3FFFFu), m.y);
    }
}

// ---------------- bf16 CSR pull: wave per row, 8 groups x 8 lanes ----------------
// Each lane loads uint4 = 16B = 8 bf16 (8 lanes cover the 128B source row).
// 8 parallel edges per wave x 2-deep unroll = 16 independent gathers in
// flight per wave. Cross-group reduce: 3-level shfl_xor.
#define BF16_FMA8(u4, v)                                                     \
    do {                                                                     \
        acc[0] = fmaf(v, __uint_as_float((u4).x << 16), acc[0]);             \
        acc[1] = fmaf(v, __uint_as_float((u4).x & 0xFFFF0000u), acc[1]);     \
        acc[2] = fmaf(v, __uint_as_float((u4).y << 16), acc[2]);             \
        acc[3] = fmaf(v, __uint_as_float((u4).y & 0xFFFF0000u), acc[3]);     \
        acc[4] = fmaf(v, __uint_as_float((u4).z << 16), acc[4]);             \
        acc[5] = fmaf(v, __uint_as_float((u4).z & 0xFFFF0000u), acc[5]);     \
        acc[6] = fmaf(v, __uint_as_float((u4).w << 16), acc[6]);             \
        acc[7] = fmaf(v, __uint_as_float((u4).w & 0xFFFF0000u), acc[7]);     \
    } while (0)

template <int WRITE_BF16>
__global__ __launch_bounds__(256) void pull_bf16_kernel(
    const int* __restrict__ rowptr, const int2* __restrict__ cc,
    const unsigned short* __restrict__ xb_prev,  // bf16 combined prev layer
    const float4* __restrict__ ue4, const float4* __restrict__ ie4,
    float4* __restrict__ outL4,                  // combined f32 output layer
    ushort4* __restrict__ xb_next)               // bf16 table for next layer
{
    int gid = blockIdx.x * 256 + threadIdx.x;
    int r = gid >> 6;
    if (r >= TROWS) return;
    int lane = threadIdx.x & 63;
    int g = lane >> 3;        // edge slot within wave: 0..7
    int sub = lane & 7;       // 16B (8-bf16) slot within feature row

    float acc[8];
#pragma unroll
    for (int j = 0; j < 8; ++j) acc[j] = 0.f;

    int end = rowptr[r + 1];
    int e = rowptr[r] + g;

    // 2-deep: edges e and e+8 per iteration (per group)
    for (; e + 8 < end; e += 16) {
        int2 m0 = cc[e];
        int2 m1 = cc[e + 8];
        uint4 x0 = *(const uint4*)(xb_prev + (size_t)m0.x * DIM + sub * 8);
        uint4 x1 = *(const uint4*)(xb_prev + (size_t)m1.x * DIM + sub * 8);
        float v0 = __int_as_float(m0.y);
        float v1 = __int_as_float(m1.y);
        BF16_FMA8(x0, v0);
        BF16_FMA8(x1, v1);
    }
    if (e < end) {
        int2 m0 = cc[e];
        uint4 x0 = *(const uint4*)(xb_prev + (size_t)m0.x * DIM + sub * 8);
        float v0 = __int_as_float(m0.y);
        BF16_FMA8(x0, v0);
    }

    // reduce the 8 edge-groups: lanes {sub, sub+8, ..., sub+56}
#pragma unroll
    for (int j = 0; j < 8; ++j) {
        acc[j] += __shfl_xor(acc[j], 8, 64);
        acc[j] += __shfl_xor(acc[j], 16, 64);
        acc[j] += __shfl_xor(acc[j], 32, 64);
    }

    if (g == 0) {
        // lane sub owns elements [sub*8, sub*8+8) = float4 slots 2*sub, 2*sub+1
        size_t base4 = (size_t)r * 16 + sub * 2;
        const float4* e0p = (r < NUSERS) ? (ue4 + base4)
                                         : (ie4 + ((size_t)(r - NUSERS) * 16 + sub * 2));
        float4 e0a = e0p[0];
        float4 e0b = e0p[1];
        float4 oa, ob;
        oa.x = fmaf(ALPHA, e0a.x, acc[0]);
        oa.y = fmaf(ALPHA, e0a.y, acc[1]);
        oa.z = fmaf(ALPHA, e0a.z, acc[2]);
        oa.w = fmaf(ALPHA, e0a.w, acc[3]);
        ob.x = fmaf(ALPHA, e0b.x, acc[4]);
        ob.y = fmaf(ALPHA, e0b.y, acc[5]);
        ob.z = fmaf(ALPHA, e0b.z, acc[6]);
        ob.w = fmaf(ALPHA, e0b.w, acc[7]);
        outL4[base4] = oa;
        outL4[base4 + 1] = ob;
        if (WRITE_BF16) {
            ushort4 ba, bb;
            ba.x = f2bf(oa.x); ba.y = f2bf(oa.y); ba.z = f2bf(oa.z); ba.w = f2bf(oa.w);
            bb.x = f2bf(ob.x); bb.y = f2bf(ob.y); bb.z = f2bf(ob.z); bb.w = f2bf(ob.w);
            xb_next[base4] = ba;
            xb_next[base4 + 1] = bb;
        }
    }
}

// ---------------- f32 CSR pull (fallback path): wave per row, 4x16 ----------------
__global__ __launch_bounds__(256) void pull_f32_kernel(
    const int* __restrict__ rowptr, const int2* __restrict__ cc,
    const float* __restrict__ xf_prev,
    const float4* __restrict__ ue4, const float4* __restrict__ ie4,
    float4* __restrict__ outL4)
{
    int gid = blockIdx.x * 256 + threadIdx.x;
    int r = gid >> 6;
    if (r >= TROWS) return;
    int lane = threadIdx.x & 63;
    int g = lane >> 4;
    int sub = lane & 15;

    float4 acc = make_float4(0.f, 0.f, 0.f, 0.f);
    int end = rowptr[r + 1];
    int e = rowptr[r] + g;

    for (; e + 4 < end; e += 8) {
        int2 m0 = cc[e];
        int2 m1 = cc[e + 4];
        float4 x0 = *(const float4*)(xf_prev + (size_t)m0.x * DIM + sub * 4);
        float4 x1 = *(const float4*)(xf_prev + (size_t)m1.x * DIM + sub * 4);
        float v0 = __int_as_float(m0.y);
        float v1 = __int_as_float(m1.y);
        acc.x = fmaf(v0, x0.x, acc.x);
        acc.y = fmaf(v0, x0.y, acc.y);
        acc.z = fmaf(v0, x0.z, acc.z);
        acc.w = fmaf(v0, x0.w, acc.w);
        acc.x = fmaf(v1, x1.x, acc.x);
        acc.y = fmaf(v1, x1.y, acc.y);
        acc.z = fmaf(v1, x1.z, acc.z);
        acc.w = fmaf(v1, x1.w, acc.w);
    }
    if (e < end) {
        int2 m0 = cc[e];
        float4 x0 = *(const float4*)(xf_prev + (size_t)m0.x * DIM + sub * 4);
        float v0 = __int_as_float(m0.y);
        acc.x = fmaf(v0, x0.x, acc.x);
        acc.y = fmaf(v0, x0.y, acc.y);
        acc.z = fmaf(v0, x0.z, acc.z);
        acc.w = fmaf(v0, x0.w, acc.w);
    }

    acc.x += __shfl_xor(acc.x, 16, 64);
    acc.y += __shfl_xor(acc.y, 16, 64);
    acc.z += __shfl_xor(acc.z, 16, 64);
    acc.w += __shfl_xor(acc.w, 16, 64);
    acc.x += __shfl_xor(acc.x, 32, 64);
    acc.y += __shfl_xor(acc.y, 32, 64);
    acc.z += __shfl_xor(acc.z, 32, 64);
    acc.w += __shfl_xor(acc.w, 32, 64);

    if (g == 0) {
        float4 e0 = (r < NUSERS) ? ue4[(size_t)r * 16 + sub]
                                 : ie4[(size_t)(r - NUSERS) * 16 + sub];
        acc.x = fmaf(ALPHA, e0.x, acc.x);
        acc.y = fmaf(ALPHA, e0.y, acc.y);
        acc.z = fmaf(ALPHA, e0.z, acc.z);
        acc.w = fmaf(ALPHA, e0.w, acc.w);
        outL4[(size_t)r * 16 + sub] = acc;
    }
}

// ---------------- fallback (round-1 atomic path) ----------------
__global__ __launch_bounds__(256) void init_out_kernel(const float4* __restrict__ ue,
                                                       const float4* __restrict__ ie,
                                                       float4* __restrict__ out) {
    const int nU4 = NUSERS * DIM / 4;
    const int nT4 = TROWS * DIM / 4;
    int i = blockIdx.x * 256 + threadIdx.x;
    if (i >= nT4) return;
    float4 v = (i < nU4) ? ue[i] : ie[i - nU4];
    out[i] = v;
    float4 a = make_float4(ALPHA * v.x, ALPHA * v.y, ALPHA * v.z, ALPHA * v.w);
    out[nT4 + i] = a;
    out[2 * nT4 + i] = a;
}

__global__ __launch_bounds__(256) void spmm_layer_kernel(
    const int* __restrict__ ui_rows, const int* __restrict__ ui_cols,
    const float* __restrict__ ui_vals,
    const int* __restrict__ iu_rows, const int* __restrict__ iu_cols,
    const float* __restrict__ iu_vals,
    const float* __restrict__ x_items, const float* __restrict__ x_users,
    float* __restrict__ y_users, float* __restrict__ y_items)
{
    unsigned tid = blockIdx.x * 256u + threadIdx.x;
    unsigned d = tid & 63u;
    unsigned e = tid >> 6;
    if (e < NNZ) {
        int r = ui_rows[e];
        int c = ui_cols[e];
        float v = ui_vals[e];
        atomicAdd(&y_users[r * DIM + d], v * x_items[c * DIM + d]);
    } else {
        e -= NNZ;
        if (e < NNZ) {
            int r = iu_rows[e];
            int c = iu_cols[e];
            float v = iu_vals[e];
            atomicAdd(&y_items[r * DIM + d], v * x_users[c * DIM + d]);
        }
    }
}

extern "C" void kernel_launch(void* const* d_in, const int* in_sizes, int n_in,
                              void* d_out, int out_size, void* d_ws, size_t ws_size,
                              hipStream_t stream) {
    const float* ue      = (const float*)d_in[0];
    const float* ie      = (const float*)d_in[1];
    const float* ui_vals = (const float*)d_in[2];
    const float* iu_vals = (const float*)d_in[3];
    const int*   ui_rows = (const int*)d_in[4];
    const int*   ui_cols = (const int*)d_in[5];
    const int*   iu_rows = (const int*)d_in[6];
    const int*   iu_cols = (const int*)d_in[7];
    float* out = (float*)d_out;

    float* L1 = out + (size_t)LSTRIDE;
    float* L2 = out + (size_t)2 * LSTRIDE;

    // ws layout: gcounts[1280] gbase[1280] gcursor[1280] rowptr[150032]
    //            | binned int2[NEDGES] | binned2 int2[NEDGES]
    //            | xb0 ushort[TROWS*64] | xb1 ushort[TROWS*64]
    const size_t NB_PAD = 1280;
    const size_t RP_PAD = 150032;
    const size_t hdr_bytes    = (NB_PAD * 3 + RP_PAD) * 4;   // 615488, 16B-aligned
    const size_t binned_bytes = (size_t)NEDGES * 8;          // 25.6 MB
    const size_t xb_bytes     = (size_t)TROWS * DIM * 2;     // 19.2 MB
    const size_t need_f32  = hdr_bytes + 2 * binned_bytes;             // ~51.8 MB
    const size_t need_bf16 = need_f32 + 2 * xb_bytes;                  // ~90.2 MB

    if (ws_size < need_f32) {
        // last-resort fallback: atomic scatter path (round-1, known-good)
        const int nT4 = TROWS * DIM / 4;
        init_out_kernel<<<(nT4 + 255) / 256, 256, 0, stream>>>(
            (const float4*)ue, (const float4*)ie, (float4*)out);
        float* u1 = L1; float* i1 = L1 + (size_t)NUSERS * DIM;
        float* u2 = L2; float* i2 = L2 + (size_t)NUSERS * DIM;
        const unsigned nblocks = (2u * NNZ * 64u) / 256u;
        spmm_layer_kernel<<<nblocks, 256, 0, stream>>>(
            ui_rows, ui_cols, ui_vals, iu_rows, iu_cols, iu_vals, ie, ue, u1, i1);
        spmm_layer_kernel<<<nblocks, 256, 0, stream>>>(
            ui_rows, ui_cols, ui_vals, iu_rows, iu_cols, iu_vals, i1, u1, u2, i2);
        return;
    }

    int* gcounts = (int*)d_ws;
    int* gbase   = gcounts + NB_PAD;
    int* gcursor = gbase + NB_PAD;
    int* rowptr  = gcursor + NB_PAD;
    int2* binned  = (int2*)((char*)d_ws + hdr_bytes);
    int2* binned2 = (int2*)((char*)binned + binned_bytes);
    unsigned short* xb0 = (unsigned short*)((char*)binned2 + binned_bytes);
    unsigned short* xb1 = xb0 + (size_t)TROWS * DIM;

    const bool use_bf16 = (ws_size >= need_bf16);

    hipMemsetAsync(gcounts, 0, NB_PAD * sizeof(int), stream);

    const int nT4 = TROWS * DIM / 4;
    if (use_bf16)
        init_copy_kernel<1><<<(nT4 + 255) / 256, 256, 0, stream>>>(
            (const float4*)ue, (const float4*)ie, (float4*)out, (ushort4*)xb0);
    else
        init_copy_kernel<0><<<(nT4 + 255) / 256, 256, 0, stream>>>(
            (const float4*)ue, (const float4*)ie, (float4*)out, nullptr);

    bucket_hist_kernel<<<NCHUNK_H, 256, 0, stream>>>(ui_rows, iu_rows, gcounts);
    scan_buckets_kernel<<<1, 64, 0, stream>>>(gcounts, gbase, gcursor, rowptr);
    bin_scatter_kernel<<<NCHUNK_S, 512, 0, stream>>>(
        ui_rows, ui_cols, ui_vals, iu_rows, iu_cols, iu_vals, gcursor, binned);
    csr_sort_kernel<<<NBUCK, 512, 0, stream>>>(gbase, gcounts, binned, binned2, rowptr);

    const float4* ue4 = (const float4*)ue;
    const float4* ie4 = (const float4*)ie;
    const int pgrid = (TROWS * DIM) / 256;   // 37500 blocks
    if (use_bf16) {
        pull_bf16_kernel<1><<<pgrid, 256, 0, stream>>>(
            rowptr, binned2, xb0, ue4, ie4, (float4*)L1, (ushort4*)xb1);
        pull_bf16_kernel<0><<<pgrid, 256, 0, stream>>>(
            rowptr, binned2, xb1, ue4, ie4, (float4*)L2, nullptr);
    } else {
        pull_f32_kernel<<<pgrid, 256, 0, stream>>>(
            rowptr, binned2, out, ue4, ie4, (float4*)L1);
        pull_f32_kernel<<<pgrid, 256, 0, stream>>>(
            rowptr, binned2, L1, ue4, ie4, (float4*)L2);
    }
}